// Round 5
// baseline (176.887 us; speedup 1.0000x reference)
//
#include <hip/hip_runtime.h>
#include <hip/hip_bf16.h>

#define T_DIM 2048
#define N_DIM 128
#define K_DIM 256
#define C_DIM 40
#define SEG 256
#define SEGLEN 8      // T_DIM / SEG
#define GRP 8
#define SEGPERGRP 32  // SEG / GRP

typedef __attribute__((ext_vector_type(8))) short bf16x8;
typedef __attribute__((ext_vector_type(4))) float f32x4v;

__device__ __forceinline__ unsigned pack_bf16(float a, float b) {
    union { float f; unsigned u; } ua, ub;
    ua.f = a; ub.f = b;
    unsigned ra = (ua.u + 0x7FFFu + ((ua.u >> 16) & 1u)) >> 16;
    unsigned rb = (ub.u + 0x7FFFu + ((ub.u >> 16) & 1u)) >> 16;
    return (ra & 0xFFFFu) | (rb << 16);
}

__device__ __forceinline__ float fast_tanh(float v) {
    float e = __expf(2.f * v);
    return 1.f - 2.f / (e + 1.f);
}

// ---------------- Phase 1: y = 5*tanh(x W^T + b) ---------------------------
// W in registers (24 bf16x8/lane). x staged global->VGPR->LDS (ds_write with
// swizzled per-lane addr), half-tile (16rows x 128 f32 = 8KB) at a time,
// software-pipelined via named reg sets rA/rB. NO inline asm, NO barriers:
// compiler emits precise counted vmcnt waits from VGPR dependencies.
// Tiles grid-strided (t*2048+gw) so the whole grid sweeps one contiguous
// 32MB window per step (m13 copy pattern).
__global__ __launch_bounds__(256, 2) void k_gemm_tanh(
    const float* __restrict__ x, const float* __restrict__ W,
    const float* __restrict__ b, float* __restrict__ y)
{
    __shared__ __align__(16) float shX[4][16][128];   // 8KB per wave, single buf

    const int tid = threadIdx.x;
    const int lane = tid & 63;
    const int wave = tid >> 6;
    const int lr = lane & 15;      // x-row within tile / W-row within c-block
    const int kg = lane >> 4;      // k-chunk group 0..3
    const int gw = blockIdx.x * 4 + wave;   // 0..2047
    const int aswz = (lr & 7) << 4;
    const int lhalf = lane >> 5;            // row parity this lane loads/writes
    const int loff = (lane & 31) * 16;      // byte offset within 512B half-row

    // ---- W fragments in registers (one-time, L2-cached) ----
    bf16x8 wf[3][8];
    #pragma unroll
    for (int cb = 0; cb < 3; ++cb) {
        #pragma unroll
        for (int kk = 0; kk < 8; ++kk) {
            int rowc = cb * 16 + lr;
            float4 w0 = {0.f, 0.f, 0.f, 0.f}, w1 = {0.f, 0.f, 0.f, 0.f};
            if (rowc < C_DIM) {
                const float* wp = W + rowc * K_DIM + kg * 8 + kk * 32;
                w0 = *reinterpret_cast<const float4*>(wp);
                w1 = *reinterpret_cast<const float4*>(wp + 4);
            }
            union { bf16x8 v; unsigned u[4]; } uw;
            uw.u[0] = pack_bf16(w0.x, w0.y);
            uw.u[1] = pack_bf16(w0.z, w0.w);
            uw.u[2] = pack_bf16(w1.x, w1.y);
            uw.u[3] = pack_bf16(w1.z, w1.w);
            wf[cb][kk] = uw.v;
        }
    }

    float4 bia0 = *reinterpret_cast<const float4*>(b + kg * 4);
    float4 bia1 = *reinterpret_cast<const float4*>(b + 16 + kg * 4);
    float4 bia2 = {0.f, 0.f, 0.f, 0.f};
    if (kg < 2) bia2 = *reinterpret_cast<const float4*>(b + 32 + kg * 4);

    const char* xb = reinterpret_cast<const char*>(x);
    char* lds = reinterpret_cast<char*>(&shX[wave][0][0]);

    float4 rA[8], rB[8];

// load 8x float4: half kh of tile (t*2048+gw) -> register set R
#define LOAD8(R, t, kh)                                                        \
    do {                                                                       \
        const char* base_ = xb + ((size_t)(t) * 2048 + gw) * 16384 + (kh) * 512; \
        _Pragma("unroll")                                                      \
        for (int j = 0; j < 8; ++j)                                            \
            R[j] = *reinterpret_cast<const float4*>(base_ + (2 * j + lhalf) * 1024 + loff); \
    } while (0)

// ds_write register set R into the wave's buffer (swizzled)
#define WRITE8(R)                                                              \
    do {                                                                       \
        _Pragma("unroll")                                                      \
        for (int j = 0; j < 8; ++j) {                                          \
            int row_ = 2 * j + lhalf;                                          \
            int adr_ = row_ * 512 + (loff ^ ((row_ & 7) << 4));                \
            *reinterpret_cast<float4*>(lds + adr_) = R[j];                     \
        }                                                                      \
    } while (0)

// one k-half of MFMAs from the buffer (KH selects W fragments only)
#define COMPUTE_HALF(KH)                                                       \
    do {                                                                       \
        _Pragma("unroll")                                                      \
        for (int kt = 0; kt < 4; ++kt) {                                       \
            int k0 = kg * 32 + kt * 128;                                       \
            float4 d0 = *reinterpret_cast<const float4*>(lds + lr * 512 + (k0 ^ aswz));        \
            float4 d1 = *reinterpret_cast<const float4*>(lds + lr * 512 + ((k0 + 16) ^ aswz)); \
            union { bf16x8 v; unsigned u[4]; } xf;                             \
            xf.u[0] = pack_bf16(d0.x, d0.y);                                   \
            xf.u[1] = pack_bf16(d0.z, d0.w);                                   \
            xf.u[2] = pack_bf16(d1.x, d1.y);                                   \
            xf.u[3] = pack_bf16(d1.z, d1.w);                                   \
            acc0 = __builtin_amdgcn_mfma_f32_16x16x32_bf16(wf[0][(KH) * 4 + kt], xf.v, acc0, 0, 0, 0); \
            acc1 = __builtin_amdgcn_mfma_f32_16x16x32_bf16(wf[1][(KH) * 4 + kt], xf.v, acc1, 0, 0, 0); \
            acc2 = __builtin_amdgcn_mfma_f32_16x16x32_bf16(wf[2][(KH) * 4 + kt], xf.v, acc2, 0, 0, 0); \
        }                                                                      \
    } while (0)

    LOAD8(rA, 0, 0);

    for (int t = 0; t < 8; ++t) {
        f32x4v acc0 = {0.f, 0.f, 0.f, 0.f};
        f32x4v acc1 = {0.f, 0.f, 0.f, 0.f};
        f32x4v acc2 = {0.f, 0.f, 0.f, 0.f};

        LOAD8(rB, t, 1);      // in flight during write+compute of half 0
        WRITE8(rA);           // compiler: waitcnt counts rB's loads, keeps them flying
        COMPUTE_HALF(0);

        if (t < 7) LOAD8(rA, t + 1, 0);  // in flight during half 1 + epilogue
        WRITE8(rB);
        COMPUTE_HALF(1);

        // epilogue: bias + tanh + store. D layout: x-row = lane&15, c = kg*4+reg
        size_t row = ((size_t)t * 2048 + gw) * 16 + lr;
        float* yr = y + row * C_DIM;
        float4 o0, o1;
        o0.x = 5.f * fast_tanh(acc0[0] + bia0.x);
        o0.y = 5.f * fast_tanh(acc0[1] + bia0.y);
        o0.z = 5.f * fast_tanh(acc0[2] + bia0.z);
        o0.w = 5.f * fast_tanh(acc0[3] + bia0.w);
        o1.x = 5.f * fast_tanh(acc1[0] + bia1.x);
        o1.y = 5.f * fast_tanh(acc1[1] + bia1.y);
        o1.z = 5.f * fast_tanh(acc1[2] + bia1.z);
        o1.w = 5.f * fast_tanh(acc1[3] + bia1.w);
        *reinterpret_cast<float4*>(yr + kg * 4) = o0;
        *reinterpret_cast<float4*>(yr + 16 + kg * 4) = o1;
        if (kg < 2) {
            float4 o2;
            o2.x = 5.f * fast_tanh(acc2[0] + bia2.x);
            o2.y = 5.f * fast_tanh(acc2[1] + bia2.y);
            o2.z = 5.f * fast_tanh(acc2[2] + bia2.z);
            o2.w = 5.f * fast_tanh(acc2[3] + bia2.w);
            *reinterpret_cast<float4*>(yr + 32 + kg * 4) = o2;
        }
    }
#undef LOAD8
#undef WRITE8
#undef COMPUTE_HALF
}

// ---------------- Phase 2a: per-segment 8x8 transition matrices ------------
__global__ __launch_bounds__(128) void k_seg(
    const float* __restrict__ y, float* __restrict__ segv, float* __restrict__ segl)
{
    int tid = blockIdx.x * 128 + threadIdx.x;   // 32768 total
    int n = tid & 127;
    int s = tid >> 7;

    float P[8][8];   // P[state j][init column c]
    #pragma unroll
    for (int j = 0; j < 8; ++j)
        #pragma unroll
        for (int c = 0; c < 8; ++c) P[j][c] = (j == c) ? 1.f : 0.f;

    for (int st = 0; st < SEGLEN; ++st) {
        int t = s * SEGLEN + st;
        const float* yr = y + ((size_t)t * N_DIM + n) * C_DIM;
        float e[40];
        #pragma unroll
        for (int i = 0; i < 10; ++i) {
            float4 v = reinterpret_cast<const float4*>(yr)[i];
            e[i * 4 + 0] = __expf(v.x);
            e[i * 4 + 1] = __expf(v.y);
            e[i * 4 + 2] = __expf(v.z);
            e[i * 4 + 3] = __expf(v.w);
        }
        #pragma unroll
        for (int c = 0; c < 8; ++c) {
            float np[8];
            #pragma unroll
            for (int j = 0; j < 4; ++j) {       // flip: all 8 sources
                float a = 0.f;
                #pragma unroll
                for (int i = 0; i < 8; ++i) a += P[i][c] * e[j * 8 + i];
                np[j] = a;
            }
            #pragma unroll
            for (int j = 0; j < 4; ++j)         // flop: 2 sources
                np[4 + j] = P[j][c] * e[32 + j] + P[4 + j][c] * e[36 + j];
            #pragma unroll
            for (int j = 0; j < 8; ++j) P[j][c] = np[j];
        }
    }
    #pragma unroll
    for (int c = 0; c < 8; ++c) {
        float sum = 0.f;
        #pragma unroll
        for (int j = 0; j < 8; ++j) sum += P[j][c];
        float inv = 1.f / sum;
        #pragma unroll
        for (int j = 0; j < 8; ++j)
            segv[(((size_t)s * 8 + c) * 8 + j) * N_DIM + n] = P[j][c] * inv;
        segl[((size_t)s * 8 + c) * N_DIM + n] = __logf(sum);
    }
}

// ---------------- Phase 2b: combine 32 segments per group ------------------
__global__ __launch_bounds__(256) void k_grp(
    const float* __restrict__ segv, const float* __restrict__ segl,
    float* __restrict__ grpv, float* __restrict__ grpl)
{
    int tid = blockIdx.x * 256 + threadIdx.x;  // 8192 total
    int n = tid & 127;
    int cc = (tid >> 7) & 7;
    int g = tid >> 10;

    float u[8];
    #pragma unroll
    for (int i = 0; i < 8; ++i) u[i] = (i == cc) ? 1.f : 0.f;
    float logacc = 0.f;

    for (int s = g * SEGPERGRP; s < (g + 1) * SEGPERGRP; ++s) {
        float l[8];
        #pragma unroll
        for (int i = 0; i < 8; ++i) l[i] = segl[((size_t)s * 8 + i) * N_DIM + n];
        float m = l[0];
        #pragma unroll
        for (int i = 1; i < 8; ++i) m = fmaxf(m, l[i]);
        float nu[8] = {0.f, 0.f, 0.f, 0.f, 0.f, 0.f, 0.f, 0.f};
        #pragma unroll
        for (int i = 0; i < 8; ++i) {
            float wi = u[i] * __expf(l[i] - m);
            #pragma unroll
            for (int j = 0; j < 8; ++j)
                nu[j] += wi * segv[(((size_t)s * 8 + i) * 8 + j) * N_DIM + n];
        }
        float sum = 0.f;
        #pragma unroll
        for (int j = 0; j < 8; ++j) sum += nu[j];
        float inv = 1.f / sum;
        #pragma unroll
        for (int j = 0; j < 8; ++j) u[j] = nu[j] * inv;
        logacc += m + __logf(sum);
    }
    #pragma unroll
    for (int j = 0; j < 8; ++j)
        grpv[(((size_t)g * 8 + cc) * 8 + j) * N_DIM + n] = u[j];
    grpl[((size_t)g * 8 + cc) * N_DIM + n] = logacc;
}

// ---------------- Phase 2c: fold 8 groups into logZ/T ----------------------
__global__ void k_fin(const float* __restrict__ grpv, const float* __restrict__ grpl,
                      float* __restrict__ lz)
{
    int n = threadIdx.x;  // 128
    float p[8] = {0.25f, 0.25f, 0.25f, 0.25f, 0.f, 0.f, 0.f, 0.f};
    float logZ = 1.3862943611198906f;  // log(4)

    for (int g = 0; g < GRP; ++g) {
        float l[8];
        #pragma unroll
        for (int i = 0; i < 8; ++i) l[i] = grpl[((size_t)g * 8 + i) * N_DIM + n];
        float m = l[0];
        #pragma unroll
        for (int i = 1; i < 8; ++i) m = fmaxf(m, l[i]);
        float nu[8] = {0.f, 0.f, 0.f, 0.f, 0.f, 0.f, 0.f, 0.f};
        #pragma unroll
        for (int i = 0; i < 8; ++i) {
            float wi = p[i] * __expf(l[i] - m);
            #pragma unroll
            for (int j = 0; j < 8; ++j)
                nu[j] += wi * grpv[(((size_t)g * 8 + i) * 8 + j) * N_DIM + n];
        }
        float sum = 0.f;
        #pragma unroll
        for (int j = 0; j < 8; ++j) sum += nu[j];
        float inv = 1.f / sum;
        #pragma unroll
        for (int j = 0; j < 8; ++j) p[j] = nu[j] * inv;
        logZ += m + __logf(sum);
    }
    lz[n] = logZ * (1.f / (float)T_DIM);
}

// ---------------- Phase 3: out -= logZ[n]/T (in place) ---------------------
__global__ __launch_bounds__(256) void k_sub(float* __restrict__ out,
                                             const float* __restrict__ lz)
{
    int i = blockIdx.x * 256 + threadIdx.x;   // float4 index; 2621440 total
    int n = (i / 10) & 127;
    float d = lz[n];
    float4* o = reinterpret_cast<float4*>(out) + i;
    float4 v = *o;
    v.x -= d; v.y -= d; v.z -= d; v.w -= d;
    *o = v;
}

extern "C" void kernel_launch(void* const* d_in, const int* in_sizes, int n_in,
                              void* d_out, int out_size, void* d_ws, size_t ws_size,
                              hipStream_t stream) {
    const float* x = (const float*)d_in[0];
    const float* W = (const float*)d_in[1];
    const float* b = (const float*)d_in[2];
    float* out = (float*)d_out;
    float* ws = (float*)d_ws;

    float* segv = ws;                  // SEG*8*8*128      = 2,097,152 f32
    float* segl = ws + 2097152;        // SEG*8*128        =   262,144 f32
    float* grpv = ws + 2359296;        // GRP*8*8*128      =    65,536 f32
    float* grpl = ws + 2424832;        // GRP*8*128        =     8,192 f32
    float* lz   = ws + 2433024;        // 128 f32

    k_gemm_tanh<<<512, 256, 0, stream>>>(x, W, b, out);   // y -> d_out
    k_seg<<<256, 128, 0, stream>>>(out, segv, segl);
    k_grp<<<32, 256, 0, stream>>>(segv, segl, grpv, grpl);
    k_fin<<<1, 128, 0, stream>>>(grpv, grpl, lz);
    k_sub<<<10240, 256, 0, stream>>>(out, lz);
}

// Round 6
// 139.722 us; speedup vs baseline: 1.2660x; 1.2660x over previous
//
#include <hip/hip_runtime.h>
#include <hip/hip_bf16.h>

#define T_DIM 2048
#define N_DIM 128
#define K_DIM 256
#define C_DIM 40
#define SEG 256
#define SEGLEN 8      // T_DIM / SEG
#define GRP 8
#define SEGPERGRP 32  // SEG / GRP

typedef __attribute__((ext_vector_type(8))) short bf16x8;
typedef __attribute__((ext_vector_type(4))) float f32x4v;

__device__ __forceinline__ unsigned pack_bf16(float a, float b) {
    union { float f; unsigned u; } ua, ub;
    ua.f = a; ub.f = b;
    unsigned ra = (ua.u + 0x7FFFu + ((ua.u >> 16) & 1u)) >> 16;
    unsigned rb = (ub.u + 0x7FFFu + ((ub.u >> 16) & 1u)) >> 16;
    return (ra & 0xFFFFu) | (rb << 16);
}

__device__ __forceinline__ float fast_tanh(float v) {
    float e = __expf(2.f * v);
    return 1.f - 2.f / (e + 1.f);
}

// ---------------- Phase 1: y = 5*tanh(x W^T + b) ---------------------------
// IDENTICAL to round-4 kernel (global_load_lds staging, W in registers,
// per-wave 2x8KB dbuf, counted vmcnt(8), no barriers) EXCEPT tile order:
// tile = t*2048 + gw (grid-stride) so at each step the WHOLE GRID reads one
// contiguous 32MB window of x (DRAM row-buffer locality, m13 copy pattern),
// instead of 2048 wave-private 128KB streams.
__global__ __launch_bounds__(256, 2) void k_gemm_tanh(
    const float* __restrict__ x, const float* __restrict__ W,
    const float* __restrict__ b, float* __restrict__ y)
{
    __shared__ __align__(16) float shX[4][2][16][128];  // per-wave dbuf, 8KB each

    const int tid = threadIdx.x;
    const int lane = tid & 63;
    const int wave = tid >> 6;
    const int lr = lane & 15;      // x-row within tile / W-row within c-block
    const int kg = lane >> 4;      // k-chunk group 0..3
    const int gw = blockIdx.x * 4 + wave;   // 0..2047
    const int aswz = (lr & 7) << 4;

    // ---- preload W fragments into registers (one-time, L2/L3 cached) ----
    bf16x8 wf[3][8];
    #pragma unroll
    for (int cb = 0; cb < 3; ++cb) {
        #pragma unroll
        for (int kk = 0; kk < 8; ++kk) {
            int rowc = cb * 16 + lr;
            float4 w0 = {0.f, 0.f, 0.f, 0.f}, w1 = {0.f, 0.f, 0.f, 0.f};
            if (rowc < C_DIM) {
                const float* wp = W + rowc * K_DIM + kg * 8 + kk * 32;
                w0 = *reinterpret_cast<const float4*>(wp);
                w1 = *reinterpret_cast<const float4*>(wp + 4);
            }
            union { bf16x8 v; unsigned u[4]; } uw;
            uw.u[0] = pack_bf16(w0.x, w0.y);
            uw.u[1] = pack_bf16(w0.z, w0.w);
            uw.u[2] = pack_bf16(w1.x, w1.y);
            uw.u[3] = pack_bf16(w1.z, w1.w);
            wf[cb][kk] = uw.v;
        }
    }

    float4 bia0 = *reinterpret_cast<const float4*>(b + kg * 4);
    float4 bia1 = *reinterpret_cast<const float4*>(b + 16 + kg * 4);
    float4 bia2 = {0.f, 0.f, 0.f, 0.f};
    if (kg < 2) bia2 = *reinterpret_cast<const float4*>(b + 32 + kg * 4);

    // issue 8 global_load_lds (1KB each) for half-tile h -> buffer h&1
    // tile index for h: (h>>1)*2048 + gw   <-- GRID-STRIDE (the one change)
    auto stage = [&](int h) {
        size_t tile = (size_t)(h >> 1) * 2048 + gw;
        const char* gbase = reinterpret_cast<const char*>(x)
                          + tile * 16384 + (h & 1) * 512;
        float* lbase = &shX[wave][h & 1][0][0];
        #pragma unroll
        for (int j = 0; j < 8; ++j) {
            int r = 2 * j + (lane >> 5);
            int off = ((lane & 31) * 16) ^ ((r & 7) << 4);  // inverse-swizzled src
            const void* gp = gbase + r * 1024 + off;
            __builtin_amdgcn_global_load_lds(
                (const __attribute__((address_space(1))) void*)gp,
                (__attribute__((address_space(3))) void*)(lbase + j * 256),
                16, 0, 0);
        }
    };

    f32x4v acc0, acc1, acc2;

// compute one k-half (KH = 0 or 1, literal): 4 kt x [2 ds_read_b128 + pack + 3 MFMA]
#define COMPUTE_HALF(KH)                                                          \
    do {                                                                          \
        const char* cX = reinterpret_cast<const char*>(&shX[wave][KH][0][0]);     \
        _Pragma("unroll")                                                         \
        for (int kt = 0; kt < 4; ++kt) {                                          \
            int k0 = kg * 32 + kt * 128;                                          \
            float4 d0 = *reinterpret_cast<const float4*>(cX + lr * 512 + (k0 ^ aswz));        \
            float4 d1 = *reinterpret_cast<const float4*>(cX + lr * 512 + ((k0 + 16) ^ aswz)); \
            union { bf16x8 v; unsigned u[4]; } xf;                                \
            xf.u[0] = pack_bf16(d0.x, d0.y);                                      \
            xf.u[1] = pack_bf16(d0.z, d0.w);                                      \
            xf.u[2] = pack_bf16(d1.x, d1.y);                                      \
            xf.u[3] = pack_bf16(d1.z, d1.w);                                      \
            acc0 = __builtin_amdgcn_mfma_f32_16x16x32_bf16(wf[0][KH * 4 + kt], xf.v, acc0, 0, 0, 0); \
            acc1 = __builtin_amdgcn_mfma_f32_16x16x32_bf16(wf[1][KH * 4 + kt], xf.v, acc1, 0, 0, 0); \
            acc2 = __builtin_amdgcn_mfma_f32_16x16x32_bf16(wf[2][KH * 4 + kt], xf.v, acc2, 0, 0, 0); \
        }                                                                         \
    } while (0)

    stage(0);
    stage(1);

    for (int t = 0; t < 8; ++t) {
        // ---- phase A: k-half 0 ----
        __builtin_amdgcn_sched_barrier(0);
        asm volatile("s_waitcnt vmcnt(8)" ::: "memory");
        __builtin_amdgcn_sched_barrier(0);
        acc0 = (f32x4v){0.f, 0.f, 0.f, 0.f};
        acc1 = (f32x4v){0.f, 0.f, 0.f, 0.f};
        acc2 = (f32x4v){0.f, 0.f, 0.f, 0.f};
        COMPUTE_HALF(0);
        __builtin_amdgcn_sched_barrier(0);
        if (t < 7) stage(2 * t + 2);

        // ---- phase B: k-half 1 ----
        __builtin_amdgcn_sched_barrier(0);
        if (t < 7) asm volatile("s_waitcnt vmcnt(8)" ::: "memory");
        else       asm volatile("s_waitcnt vmcnt(0)" ::: "memory");
        __builtin_amdgcn_sched_barrier(0);
        COMPUTE_HALF(1);

        // ---- epilogue: bias + tanh + store ----
        size_t row = ((size_t)t * 2048 + gw) * 16 + lr;
        float* yr = y + row * C_DIM;
        float4 o0, o1;
        o0.x = 5.f * fast_tanh(acc0[0] + bia0.x);
        o0.y = 5.f * fast_tanh(acc0[1] + bia0.y);
        o0.z = 5.f * fast_tanh(acc0[2] + bia0.z);
        o0.w = 5.f * fast_tanh(acc0[3] + bia0.w);
        o1.x = 5.f * fast_tanh(acc1[0] + bia1.x);
        o1.y = 5.f * fast_tanh(acc1[1] + bia1.y);
        o1.z = 5.f * fast_tanh(acc1[2] + bia1.z);
        o1.w = 5.f * fast_tanh(acc1[3] + bia1.w);
        *reinterpret_cast<float4*>(yr + kg * 4) = o0;
        *reinterpret_cast<float4*>(yr + 16 + kg * 4) = o1;
        if (kg < 2) {
            float4 o2;
            o2.x = 5.f * fast_tanh(acc2[0] + bia2.x);
            o2.y = 5.f * fast_tanh(acc2[1] + bia2.y);
            o2.z = 5.f * fast_tanh(acc2[2] + bia2.z);
            o2.w = 5.f * fast_tanh(acc2[3] + bia2.w);
            *reinterpret_cast<float4*>(yr + 32 + kg * 4) = o2;
        }

        __builtin_amdgcn_sched_barrier(0);
        if (t < 7) stage(2 * t + 3);
    }
#undef COMPUTE_HALF
}

// ---------------- Phase 2a: per-segment 8x8 transition matrices ------------
__global__ __launch_bounds__(128) void k_seg(
    const float* __restrict__ y, float* __restrict__ segv, float* __restrict__ segl)
{
    int tid = blockIdx.x * 128 + threadIdx.x;   // 32768 total
    int n = tid & 127;
    int s = tid >> 7;

    float P[8][8];   // P[state j][init column c]
    #pragma unroll
    for (int j = 0; j < 8; ++j)
        #pragma unroll
        for (int c = 0; c < 8; ++c) P[j][c] = (j == c) ? 1.f : 0.f;

    for (int st = 0; st < SEGLEN; ++st) {
        int t = s * SEGLEN + st;
        const float* yr = y + ((size_t)t * N_DIM + n) * C_DIM;
        float e[40];
        #pragma unroll
        for (int i = 0; i < 10; ++i) {
            float4 v = reinterpret_cast<const float4*>(yr)[i];
            e[i * 4 + 0] = __expf(v.x);
            e[i * 4 + 1] = __expf(v.y);
            e[i * 4 + 2] = __expf(v.z);
            e[i * 4 + 3] = __expf(v.w);
        }
        #pragma unroll
        for (int c = 0; c < 8; ++c) {
            float np[8];
            #pragma unroll
            for (int j = 0; j < 4; ++j) {       // flip: all 8 sources
                float a = 0.f;
                #pragma unroll
                for (int i = 0; i < 8; ++i) a += P[i][c] * e[j * 8 + i];
                np[j] = a;
            }
            #pragma unroll
            for (int j = 0; j < 4; ++j)         // flop: 2 sources
                np[4 + j] = P[j][c] * e[32 + j] + P[4 + j][c] * e[36 + j];
            #pragma unroll
            for (int j = 0; j < 8; ++j) P[j][c] = np[j];
        }
    }
    #pragma unroll
    for (int c = 0; c < 8; ++c) {
        float sum = 0.f;
        #pragma unroll
        for (int j = 0; j < 8; ++j) sum += P[j][c];
        float inv = 1.f / sum;
        #pragma unroll
        for (int j = 0; j < 8; ++j)
            segv[(((size_t)s * 8 + c) * 8 + j) * N_DIM + n] = P[j][c] * inv;
        segl[((size_t)s * 8 + c) * N_DIM + n] = __logf(sum);
    }
}

// ---------------- Phase 2b: combine 32 segments per group ------------------
__global__ __launch_bounds__(256) void k_grp(
    const float* __restrict__ segv, const float* __restrict__ segl,
    float* __restrict__ grpv, float* __restrict__ grpl)
{
    int tid = blockIdx.x * 256 + threadIdx.x;  // 8192 total
    int n = tid & 127;
    int cc = (tid >> 7) & 7;
    int g = tid >> 10;

    float u[8];
    #pragma unroll
    for (int i = 0; i < 8; ++i) u[i] = (i == cc) ? 1.f : 0.f;
    float logacc = 0.f;

    for (int s = g * SEGPERGRP; s < (g + 1) * SEGPERGRP; ++s) {
        float l[8];
        #pragma unroll
        for (int i = 0; i < 8; ++i) l[i] = segl[((size_t)s * 8 + i) * N_DIM + n];
        float m = l[0];
        #pragma unroll
        for (int i = 1; i < 8; ++i) m = fmaxf(m, l[i]);
        float nu[8] = {0.f, 0.f, 0.f, 0.f, 0.f, 0.f, 0.f, 0.f};
        #pragma unroll
        for (int i = 0; i < 8; ++i) {
            float wi = u[i] * __expf(l[i] - m);
            #pragma unroll
            for (int j = 0; j < 8; ++j)
                nu[j] += wi * segv[(((size_t)s * 8 + i) * 8 + j) * N_DIM + n];
        }
        float sum = 0.f;
        #pragma unroll
        for (int j = 0; j < 8; ++j) sum += nu[j];
        float inv = 1.f / sum;
        #pragma unroll
        for (int j = 0; j < 8; ++j) u[j] = nu[j] * inv;
        logacc += m + __logf(sum);
    }
    #pragma unroll
    for (int j = 0; j < 8; ++j)
        grpv[(((size_t)g * 8 + cc) * 8 + j) * N_DIM + n] = u[j];
    grpl[((size_t)g * 8 + cc) * N_DIM + n] = logacc;
}

// ---------------- Phase 2c: fold 8 groups into logZ/T ----------------------
__global__ void k_fin(const float* __restrict__ grpv, const float* __restrict__ grpl,
                      float* __restrict__ lz)
{
    int n = threadIdx.x;  // 128
    float p[8] = {0.25f, 0.25f, 0.25f, 0.25f, 0.f, 0.f, 0.f, 0.f};
    float logZ = 1.3862943611198906f;  // log(4)

    for (int g = 0; g < GRP; ++g) {
        float l[8];
        #pragma unroll
        for (int i = 0; i < 8; ++i) l[i] = grpl[((size_t)g * 8 + i) * N_DIM + n];
        float m = l[0];
        #pragma unroll
        for (int i = 1; i < 8; ++i) m = fmaxf(m, l[i]);
        float nu[8] = {0.f, 0.f, 0.f, 0.f, 0.f, 0.f, 0.f, 0.f};
        #pragma unroll
        for (int i = 0; i < 8; ++i) {
            float wi = p[i] * __expf(l[i] - m);
            #pragma unroll
            for (int j = 0; j < 8; ++j)
                nu[j] += wi * grpv[(((size_t)g * 8 + i) * 8 + j) * N_DIM + n];
        }
        float sum = 0.f;
        #pragma unroll
        for (int j = 0; j < 8; ++j) sum += nu[j];
        float inv = 1.f / sum;
        #pragma unroll
        for (int j = 0; j < 8; ++j) p[j] = nu[j] * inv;
        logZ += m + __logf(sum);
    }
    lz[n] = logZ * (1.f / (float)T_DIM);
}

// ---------------- Phase 3: out -= logZ[n]/T (in place) ---------------------
__global__ __launch_bounds__(256) void k_sub(float* __restrict__ out,
                                             const float* __restrict__ lz)
{
    int i = blockIdx.x * 256 + threadIdx.x;   // float4 index; 2621440 total
    int n = (i / 10) & 127;
    float d = lz[n];
    float4* o = reinterpret_cast<float4*>(out) + i;
    float4 v = *o;
    v.x -= d; v.y -= d; v.z -= d; v.w -= d;
    *o = v;
}

extern "C" void kernel_launch(void* const* d_in, const int* in_sizes, int n_in,
                              void* d_out, int out_size, void* d_ws, size_t ws_size,
                              hipStream_t stream) {
    const float* x = (const float*)d_in[0];
    const float* W = (const float*)d_in[1];
    const float* b = (const float*)d_in[2];
    float* out = (float*)d_out;
    float* ws = (float*)d_ws;

    float* segv = ws;                  // SEG*8*8*128      = 2,097,152 f32
    float* segl = ws + 2097152;        // SEG*8*128        =   262,144 f32
    float* grpv = ws + 2359296;        // GRP*8*8*128      =    65,536 f32
    float* grpl = ws + 2424832;        // GRP*8*128        =     8,192 f32
    float* lz   = ws + 2433024;        // 128 f32

    k_gemm_tanh<<<512, 256, 0, stream>>>(x, W, b, out);   // y -> d_out
    k_seg<<<256, 128, 0, stream>>>(out, segv, segl);
    k_grp<<<32, 256, 0, stream>>>(segv, segl, grpv, grpl);
    k_fin<<<1, 128, 0, stream>>>(grpv, grpl, lz);
    k_sub<<<10240, 256, 0, stream>>>(out, lz);
}